// Round 13
// baseline (45.042 us; speedup 1.0000x reference)
//
#include <hip/hip_runtime.h>
#include <hip/hip_fp16.h>
#include <stdint.h>

#define B_    32
#define T_    1000
#define F_    80
#define COUT_ 64
#define NAUX_ 128
#define TO_   500
#define FO_   40
#define PSTR_ 12   // per-(b,c) param stride in u32: 9 dup-half2 taps + 1 f32 bias + 2 pad
#define CL_   8    // channels per block-column (register window reuse)

// ws layout (u32 indices): fw [0, 24576); O [32768, 32768+1282560); E follows.
#define OFF_O 32768
#define NO_U  (B_ * 501 * 80)      // 1,282,560 u32
#define OFF_E (OFF_O + NO_U)
#define NE_U  (B_ * 500 * 80)      // 1,280,000 u32

#define NFT (B_ * 576 * 16)        // filter-dot threads
#define NBT (B_ * 64 * 16)         // bias-dot threads
#define NPP_O (B_ * 501 * 20)      // O pre-pack tasks (dwordx4 each)
#define NPP_E (B_ * 500 * 20)      // E pre-pack tasks

typedef float v4f __attribute__((ext_vector_type(4)));
typedef _Float16 h2v __attribute__((ext_vector_type(2)));
typedef __fp16 fp16x2 __attribute__((ext_vector_type(2)));   // cvt_pkrtz return type

static __device__ __forceinline__ uint32_t pk2(float lo, float hi) {
    fp16x2 pk = __builtin_amdgcn_cvt_pkrtz(lo, hi);
    return *(uint32_t*)&pk;
}

// Kernel 1: hypernetwork dots + l2 + (optionally) f16 vertical-pair pre-pack of x.
__global__ __launch_bounds__(256) void hyper_kernel(
    const float* __restrict__ aux,
    const float* __restrict__ Wg,
    const float* __restrict__ bg,
    const float* __restrict__ Wb,
    const float* __restrict__ bb,
    const int*   __restrict__ x_len,
    const float* __restrict__ x,
    uint32_t* __restrict__ ws,       // fw + O + E
    float* __restrict__ l2_out)
{
    int t = blockIdx.x * blockDim.x + threadIdx.x;

    if (t < NFT) {
        int d = t >> 4, part = t & 15;      // 16-lane groups wave-aligned
        int b = d / 576, idx = d % 576;
        const float* a = aux + b * NAUX_ + part * 8;
        const float* w = Wg + (size_t)idx * NAUX_ + part * 8;
        float4 a0 = *(const float4*)(a);
        float4 a1 = *(const float4*)(a + 4);
        float4 w0 = *(const float4*)(w);
        float4 w1 = *(const float4*)(w + 4);
        float s = a0.x * w0.x;
        s = fmaf(a0.y, w0.y, s);
        s = fmaf(a0.z, w0.z, s);
        s = fmaf(a0.w, w0.w, s);
        s = fmaf(a1.x, w1.x, s);
        s = fmaf(a1.y, w1.y, s);
        s = fmaf(a1.z, w1.z, s);
        s = fmaf(a1.w, w1.w, s);
        s += __shfl_xor(s, 1);
        s += __shfl_xor(s, 2);
        s += __shfl_xor(s, 4);
        s += __shfl_xor(s, 8);
        if (part == 0) {
            int c = idx / 9, k = idx % 9;
            uint32_t hu = (uint32_t)__half_as_ushort(__float2half_rn(s + bg[idx]));
            ws[(b * COUT_ + c) * PSTR_ + k] = hu | (hu << 16);
        }
    } else if (t < NFT + NBT) {
        int u = t - NFT;
        int d = u >> 4, part = u & 15;
        int b = d >> 6, c = d & 63;
        const float* a = aux + b * NAUX_ + part * 8;
        const float* w = Wb + (size_t)c * NAUX_ + part * 8;
        float4 a0 = *(const float4*)(a);
        float4 a1 = *(const float4*)(a + 4);
        float4 w0 = *(const float4*)(w);
        float4 w1 = *(const float4*)(w + 4);
        float s = a0.x * w0.x;
        s = fmaf(a0.y, w0.y, s);
        s = fmaf(a0.z, w0.z, s);
        s = fmaf(a0.w, w0.w, s);
        s = fmaf(a1.x, w1.x, s);
        s = fmaf(a1.y, w1.y, s);
        s = fmaf(a1.z, w1.z, s);
        s = fmaf(a1.w, w1.w, s);
        s += __shfl_xor(s, 1);
        s += __shfl_xor(s, 2);
        s += __shfl_xor(s, 4);
        s += __shfl_xor(s, 8);
        if (part == 0) ws[d * PSTR_ + 9] = __float_as_uint(s + bb[c]);
    } else if (t < NFT + NBT + B_) {
        int b = t - NFT - NBT;
        l2_out[b] = (float)(x_len[b] >> 1);
    } else if (t < NFT + NBT + B_ + NPP_O) {
        // O[b][to][c] = pack(x[2to-1][c], x[2to][c]); to in [0,501)
        int v  = t - (NFT + NBT + B_);
        int b  = v / (501 * 20);
        int r  = v % (501 * 20);
        int to = r / 20;
        int c  = (r % 20) * 4;
        int rA = 2 * to - 1, rB = 2 * to;
        float4 a = (rA >= 0) ? *(const float4*)(x + ((size_t)b * T_ + rA) * F_ + c)
                             : make_float4(0.f, 0.f, 0.f, 0.f);
        float4 d = (rB < T_) ? *(const float4*)(x + ((size_t)b * T_ + rB) * F_ + c)
                             : make_float4(0.f, 0.f, 0.f, 0.f);
        uint4 o;
        o.x = pk2(a.x, d.x); o.y = pk2(a.y, d.y);
        o.z = pk2(a.z, d.z); o.w = pk2(a.w, d.w);
        *(uint4*)(ws + OFF_O + ((size_t)b * 501 + to) * 80 + c) = o;
    } else if (t < NFT + NBT + B_ + NPP_O + NPP_E) {
        // E[b][to][c] = pack(x[2to][c], x[2to+1][c]); to in [0,500) (no bounds issues)
        int v  = t - (NFT + NBT + B_ + NPP_O);
        int b  = v / (500 * 20);
        int r  = v % (500 * 20);
        int to = r / 20;
        int c  = (r % 20) * 4;
        const float* base = x + ((size_t)b * T_ + 2 * to) * F_ + c;
        float4 a = *(const float4*)(base);
        float4 d = *(const float4*)(base + F_);
        uint4 o;
        o.x = pk2(a.x, d.x); o.y = pk2(a.y, d.y);
        o.z = pk2(a.z, d.z); o.w = pk2(a.w, d.w);
        *(uint4*)(ws + OFF_E + ((size_t)b * 500 + to) * 80 + c) = o;
    }
}

// row loader for pre-packed pair rows: 10 u32 window cols 8f4-1..8f4+8
static __device__ __forceinline__ void load_prow(__half2* wp, const uint32_t* p, int f4) {
    uint32_t u0 = (f4 > 0) ? p[-1] : 0u;
    uint4 m0 = *(const uint4*)(p);        // 16B aligned: offset multiple of 4 u32
    uint4 m1 = *(const uint4*)(p + 4);
    uint32_t u9 = (f4 < 9) ? p[8] : 0u;
    wp[0] = *(__half2*)&u0;
    wp[1] = *(__half2*)&m0.x; wp[2] = *(__half2*)&m0.y;
    wp[3] = *(__half2*)&m0.z; wp[4] = *(__half2*)&m0.w;
    wp[5] = *(__half2*)&m1.x; wp[6] = *(__half2*)&m1.y;
    wp[7] = *(__half2*)&m1.z; wp[8] = *(__half2*)&m1.w;
    wp[9] = *(__half2*)&u9;
}

// Kernel 2: fused conv(3x3,pad1) + bias + relu + maxpool(2x2,s2) + time mask.
// PRE=true: window pair-rows loaded directly from pre-packed O/E arrays.
template<bool PRE>
__global__ __launch_bounds__(256) void conv_pool_kernel(
    const float*    __restrict__ x,
    const int*      __restrict__ x_len,
    const uint32_t* __restrict__ ws,     // fw (+ O/E when PRE)
    float* __restrict__ out)
{
    const int bg  = blockIdx.y;       // b*8 + g
    const int b   = bg >> 3;
    const int bc0 = bg * CL_;         // b*64 + g*8

    int t = blockIdx.x * blockDim.x + threadIdx.x;   // [0, 5120)
    if (t >= TO_ * 10) return;                       // 5000 active
    int f4 = t % 10;
    int to = t / 10;

    float* obase = out + ((size_t)bc0 * TO_ + to) * FO_ + 4 * f4;

    int l2 = x_len[b] >> 1;
    if (to >= l2) {
        v4f z = (v4f){0.f, 0.f, 0.f, 0.f};
        #pragma unroll
        for (int i = 0; i < CL_; ++i)
            __builtin_nontemporal_store(z, (v4f*)(obase + (size_t)i * (TO_ * FO_)));
        return;
    }

    // all channels' params up front: wave-uniform address -> s_load
    const uint32_t* p = ws + (size_t)bc0 * PSTR_;
    uint32_t prm[CL_][10];
    #pragma unroll
    for (int i = 0; i < CL_; ++i)
        #pragma unroll
        for (int k = 0; k < 10; ++k)
            prm[i][k] = p[i * PSTR_ + k];

    __half2 wp[3][10];
    const int cb = 8 * f4;

    if (PRE) {
        const uint32_t* Ob = ws + OFF_O + ((size_t)b * 501 + to) * 80 + cb;
        const uint32_t* Eb = ws + OFF_E + ((size_t)b * 500 + to) * 80 + cb;
        load_prow(wp[0], Ob, f4);        // (x[2to-1], x[2to])
        load_prow(wp[1], Eb, f4);        // (x[2to],   x[2to+1])
        load_prow(wp[2], Ob + 80, f4);   // (x[2to+1], x[2to+2])
    } else {
        float w[4][10];
        const float* xb = x + (size_t)b * (T_ * F_);
        #pragma unroll
        for (int i = 0; i < 4; ++i) {
            int r = 2 * to - 1 + i;
            if (r < 0 || r >= T_) {
                #pragma unroll
                for (int j = 0; j < 10; ++j) w[i][j] = 0.f;
            } else {
                const float* rp = xb + r * F_ + cb;
                w[i][0] = (f4 > 0) ? rp[-1] : 0.f;
                float4 m0 = *(const float4*)(rp);
                float4 m1 = *(const float4*)(rp + 4);
                w[i][1] = m0.x; w[i][2] = m0.y; w[i][3] = m0.z; w[i][4] = m0.w;
                w[i][5] = m1.x; w[i][6] = m1.y; w[i][7] = m1.z; w[i][8] = m1.w;
                w[i][9] = (f4 < 9) ? rp[8] : 0.f;
            }
        }
        #pragma unroll
        for (int ii = 0; ii < 3; ++ii)
            #pragma unroll
            for (int c = 0; c < 10; ++c) {
                uint32_t u = pk2(w[ii][c], w[ii + 1][c]);
                wp[ii][c] = *(__half2*)&u;
            }
    }

    #pragma unroll
    for (int i = 0; i < CL_; ++i) {
        __half2 flt[9];
        #pragma unroll
        for (int k = 0; k < 9; ++k)
            flt[k] = *(const __half2*)&prm[i][k];    // duplicated (h,h)
        const float bias = __uint_as_float(prm[i][9]);

        float o[4];
        #pragma unroll
        for (int q = 0; q < 4; ++q) {
            __half2 acc0 = __halves2half2(__ushort_as_half((unsigned short)0),
                                          __ushort_as_half((unsigned short)0));
            __half2 acc1 = acc0;
            #pragma unroll
            for (int ii = 0; ii < 3; ++ii) {
                #pragma unroll
                for (int jj = 0; jj < 3; ++jj) {
                    const __half2 f = flt[ii * 3 + jj];
                    acc0 = __hfma2(f, wp[ii][2 * q + jj],     acc0);  // (s00,s10)
                    acc1 = __hfma2(f, wp[ii][2 * q + 1 + jj], acc1);  // (s01,s11)
                }
            }
            h2v m2 = __builtin_elementwise_max(*(h2v*)&acc0, *(h2v*)&acc1);
            float m = fmaxf((float)m2.x, (float)m2.y);
            o[q] = fmaxf(m + bias, 0.f);
        }
        v4f ov = (v4f){o[0], o[1], o[2], o[3]};
        __builtin_nontemporal_store(ov, (v4f*)(obase + (size_t)i * (TO_ * FO_)));
    }
}

extern "C" void kernel_launch(void* const* d_in, const int* in_sizes, int n_in,
                              void* d_out, int out_size, void* d_ws, size_t ws_size,
                              hipStream_t stream) {
    const float* x     = (const float*)d_in[0];
    const int*   x_len = (const int*)d_in[1];
    const float* aux   = (const float*)d_in[2];
    const float* Wg    = (const float*)d_in[3];
    const float* bg    = (const float*)d_in[4];
    const float* Wb    = (const float*)d_in[5];
    const float* bb    = (const float*)d_in[6];

    float*    out = (float*)d_out;
    uint32_t* ws  = (uint32_t*)d_ws;
    float* l2_out = out + (size_t)B_ * COUT_ * TO_ * FO_;  // tail: 32 floats

    const size_t need = (size_t)(OFF_E + NE_U) * 4;        // ~10.4 MB
    const bool pre = (ws_size >= need);

    // Kernel 1: hyper dots + l2 (+ pre-pack tasks when ws allows)
    {
        int total = NFT + NBT + B_ + (pre ? (NPP_O + NPP_E) : 0);
        int blocks = (total + 255) / 256;
        hipLaunchKernelGGL(hyper_kernel, dim3(blocks), dim3(256), 0, stream,
                           aux, Wg, bg, Wb, bb, x_len, x, ws, l2_out);
    }
    // Kernel 2: grid (20, 256) = 5120 threads per (b,g), 256 (b,g) pairs
    if (pre) {
        hipLaunchKernelGGL((conv_pool_kernel<true>), dim3(20, 256), dim3(256), 0, stream,
                           x, x_len, ws, out);
    } else {
        hipLaunchKernelGGL((conv_pool_kernel<false>), dim3(20, 256), dim3(256), 0, stream,
                           x, x_len, ws, out);
    }
}